// Round 1
// baseline (275.935 us; speedup 1.0000x reference)
//
#include <hip/hip_runtime.h>

typedef __attribute__((ext_vector_type(8))) short bhalf8;
typedef __attribute__((ext_vector_type(4))) float floatx4;

#define ALPHA_LR 0.2f

__device__ __forceinline__ unsigned short f2bf(float f) {
  union { float f; unsigned int u; } v; v.f = f;
  unsigned int r = v.u + 0x7fffu + ((v.u >> 16) & 1u);
  return (unsigned short)(r >> 16);
}
__device__ __forceinline__ float bf2f(unsigned short u) {
  union { unsigned int u; float f; } v; v.u = ((unsigned int)u) << 16;
  return v.f;
}
// async global->LDS, 16B per lane; LDS dest is wave-uniform base + lane*16
__device__ __forceinline__ void gld16(const void* g, void* l) {
  __builtin_amdgcn_global_load_lds((const __attribute__((address_space(1))) unsigned int*)g,
                                   (__attribute__((address_space(3))) unsigned int*)l,
                                   16, 0, 0);
}

// ---------------------------------------------------------------------------
// k0w: W [k][n] fp32 -> WT_hi/WT_lo bf16, k-tiled layout [ks=8][n=256][k'=32].
// Also re-initializes s2maxEnc[8] (ws is re-poisoned before every call).
// ---------------------------------------------------------------------------
__global__ void k0w_split(const float* __restrict__ W,
                          unsigned short* __restrict__ WThi,
                          unsigned short* __restrict__ WTlo,
                          unsigned int* __restrict__ s2maxEnc) {
  __shared__ float s[16][17];
  const int tx = threadIdx.x, ty = threadIdx.y;
  if (blockIdx.x == 0 && blockIdx.y == 0 && ty == 0 && tx < 8) s2maxEnc[tx] = 0u;
  const int n0 = blockIdx.x * 16, k0 = blockIdx.y * 16;
  s[ty][tx] = W[(k0 + ty) * 256 + n0 + tx];
  __syncthreads();
  float v = s[tx][ty];  // = W[k0+tx][n0+ty]
  const int k = k0 + tx, n = n0 + ty;
  unsigned short hi = f2bf(v);
  unsigned short lo = f2bf(v - bf2f(hi));
  const int idx = (k >> 5) * 8192 + n * 32 + (k & 31);
  WThi[idx] = hi;
  WTlo[idx] = lo;
}

// ---------------------------------------------------------------------------
// k1: Wh = h @ W via split-bf16 MFMA (hi*hi + hi*lo + lo*hi), h split in-kernel.
// Writes WhPack bf16 [B][jt=64][f=256][j'=32], s1/s2 (fp32 dots with a), and
// per-batch encoded atomicMax of s2 (for the k3 softmax bound).
// ---------------------------------------------------------------------------
__global__ __launch_bounds__(512, 2) void k1_mfma(const float* __restrict__ h,
                                                  const unsigned short* __restrict__ Bhi_g,
                                                  const unsigned short* __restrict__ Blo_g,
                                                  const float* __restrict__ a_g,
                                                  unsigned short* __restrict__ WhPack,
                                                  float* __restrict__ s1,
                                                  float* __restrict__ s2,
                                                  unsigned int* __restrict__ s2maxEnc) {
  __shared__ unsigned short Ah[64 * 264], Al[64 * 264];  // 33 KB each
  __shared__ unsigned short Bh[2][8192], Bl[2][8192];    // 16 KB per buffer
  __shared__ float s1red[64], s2red[64];
  const int t = threadIdx.x;
  const long r0 = (long)blockIdx.x * 64;
  const int wave = t >> 6, lane = t & 63;

  if (t < 64) { s1red[t] = 0.f; s2red[t] = 0.f; }

#pragma unroll
  for (int rep = 0; rep < 2; rep++) {
    const int off = wave * 1024 + rep * 512;
    gld16(Bhi_g + off + lane * 8, &Bh[0][off]);
    gld16(Blo_g + off + lane * 8, &Bl[0][off]);
  }

#pragma unroll
  for (int q = 0; q < 8; q++) {
    int idx = q * 512 + t;
    int row = idx >> 6, c4 = idx & 63;
    float4 x = *(const float4*)(h + (r0 + row) * 256 + c4 * 4);
    float xs[4] = {x.x, x.y, x.z, x.w};
    unsigned short hs[4], ls[4];
#pragma unroll
    for (int qq = 0; qq < 4; qq++) {
      hs[qq] = f2bf(xs[qq]);
      ls[qq] = f2bf(xs[qq] - bf2f(hs[qq]));
    }
    *(ushort4*)&Ah[row * 264 + c4 * 4] = (ushort4){hs[0], hs[1], hs[2], hs[3]};
    *(ushort4*)&Al[row * 264 + c4 * 4] = (ushort4){ls[0], ls[1], ls[2], ls[3]};
  }
  __syncthreads();

  const int wm = wave >> 2, wn = wave & 3;
  const int lhi = lane >> 4, llo = lane & 15;

  floatx4 acc[2][4];
#pragma unroll
  for (int mt = 0; mt < 2; mt++)
#pragma unroll
    for (int nt = 0; nt < 4; nt++) acc[mt][nt] = (floatx4){0.f, 0.f, 0.f, 0.f};

  for (int ks = 0; ks < 8; ks++) {
    const int cur = ks & 1, nxt = cur ^ 1, ksn = (ks + 1) & 7;
#pragma unroll
    for (int rep = 0; rep < 2; rep++) {
      const int off = wave * 1024 + rep * 512;
      gld16(Bhi_g + ksn * 8192 + off + lane * 8, &Bh[nxt][off]);
      gld16(Blo_g + ksn * 8192 + off + lane * 8, &Bl[nxt][off]);
    }

    const int k0 = ks * 32;
    bhalf8 ah[2], al[2], bh[4], bl[4];
#pragma unroll
    for (int mt = 0; mt < 2; mt++) {
      int ro = (wm * 32 + mt * 16 + llo) * 264 + k0 + lhi * 8;
      ah[mt] = *(const bhalf8*)&Ah[ro];
      al[mt] = *(const bhalf8*)&Al[ro];
    }
#pragma unroll
    for (int nt = 0; nt < 4; nt++) {
      int ro = (wn * 64 + nt * 16 + llo) * 32 + lhi * 8;
      bh[nt] = *(const bhalf8*)&Bh[cur][ro];
      bl[nt] = *(const bhalf8*)&Bl[cur][ro];
    }
#pragma unroll
    for (int mt = 0; mt < 2; mt++)
#pragma unroll
      for (int nt = 0; nt < 4; nt++) {
        acc[mt][nt] = __builtin_amdgcn_mfma_f32_16x16x32_bf16(ah[mt], bh[nt], acc[mt][nt], 0, 0, 0);
        acc[mt][nt] = __builtin_amdgcn_mfma_f32_16x16x32_bf16(ah[mt], bl[nt], acc[mt][nt], 0, 0, 0);
        acc[mt][nt] = __builtin_amdgcn_mfma_f32_16x16x32_bf16(al[mt], bh[nt], acc[mt][nt], 0, 0, 0);
      }
    __syncthreads();
  }

  float a1v[4], a2v[4];
#pragma unroll
  for (int nt = 0; nt < 4; nt++) {
    int f = wn * 64 + nt * 16 + llo;
    a1v[nt] = a_g[f];
    a2v[nt] = a_g[256 + f];
  }

  const int b = (int)(r0 >> 11);
  const int jt_base = (int)((r0 & 2047) >> 5);

#pragma unroll
  for (int mt = 0; mt < 2; mt++) {
    float p1[4], p2[4];
#pragma unroll
    for (int reg = 0; reg < 4; reg++) {
      p1[reg] = acc[mt][0][reg] * a1v[0] + acc[mt][1][reg] * a1v[1] +
                acc[mt][2][reg] * a1v[2] + acc[mt][3][reg] * a1v[3];
      p2[reg] = acc[mt][0][reg] * a2v[0] + acc[mt][1][reg] * a2v[1] +
                acc[mt][2][reg] * a2v[2] + acc[mt][3][reg] * a2v[3];
    }
#pragma unroll
    for (int off = 1; off < 16; off <<= 1) {
#pragma unroll
      for (int reg = 0; reg < 4; reg++) {
        p1[reg] += __shfl_xor(p1[reg], off);
        p2[reg] += __shfl_xor(p2[reg], off);
      }
    }
    if (llo == 0) {
#pragma unroll
      for (int reg = 0; reg < 4; reg++) {
        int il = wm * 32 + mt * 16 + lhi * 4 + reg;
        atomicAdd(&s1red[il], p1[reg]);
        atomicAdd(&s2red[il], p2[reg]);
      }
    }
#pragma unroll
    for (int nt = 0; nt < 4; nt++) {
      int f = wn * 64 + nt * 16 + llo;
      int jt = jt_base + wm;
      ushort4 pk = (ushort4){f2bf(acc[mt][nt][0]), f2bf(acc[mt][nt][1]),
                             f2bf(acc[mt][nt][2]), f2bf(acc[mt][nt][3])};
      *(ushort4*)&WhPack[((long)((b * 64 + jt) * 256 + f)) * 32 + mt * 16 + lhi * 4] = pk;
    }
  }

  __syncthreads();
  if (t < 64) {
    s1[r0 + t] = s1red[t];
    s2[r0 + t] = s2red[t];
    // per-batch max(s2): 64-lane reduce + one encoded atomicMax per block
    float v = s2red[t];
#pragma unroll
    for (int o = 32; o; o >>= 1) v = fmaxf(v, __shfl_xor(v, o));
    if (t == 0) {
      unsigned int u = __float_as_uint(v);
      unsigned int key = (u & 0x80000000u) ? ~u : (u | 0x80000000u);
      atomicMax(s2maxEnc + b, key);
    }
  }
}

// ---------------------------------------------------------------------------
// K3 (L2-direct B): out = elu( softmax(mask(leaky(s1+s2))) @ Wh ).
// Wh per batch is 1 MB -> fits per-XCD L2. No LDS staging of Wh: each wave
// reads its 4 B-fragments straight from global (wave covers a contiguous 1 KB,
// fully coalesced; wm-pair waves read identical lines -> L1 hit), register-
// double-buffered one jt ahead. Reg-destination loads are NOT drained at
// s_barrier, so L2 latency hides under the current jt's MFMA + next-P compute.
// XCD-affine swizzle: b = lin&7 so all 64 blocks of batch b land on XCD b
// (round-robin dispatch), keeping that batch's Wh L2-resident.
// Only P (32x32 bf16, 2-buf) + s2all remain in LDS (~13.3 KB).
// grid (64, 8) x 512 thr; block 32 rows x 256 f; wave tile 16 x 64.
// ---------------------------------------------------------------------------
__global__ __launch_bounds__(512, 4) void k3_attn(const unsigned short* __restrict__ WhPack,
                                                  const int* __restrict__ adj,
                                                  const float* __restrict__ s1g,
                                                  const float* __restrict__ s2g,
                                                  const unsigned int* __restrict__ s2maxEnc,
                                                  float* __restrict__ out) {
  const int t = threadIdx.x;
  const int lin = blockIdx.y * 64 + blockIdx.x;
  const int b = lin & 7;             // XCD-affine: dispatch round-robin -> XCD = lin%8
  const int i0 = (lin >> 3) * 32;
  const long gr0 = (long)b * 2048 + i0;

  __shared__ float s2all[2048];          // 8 KB
  __shared__ unsigned short P[2][1280];  // [i=32][j' pad 40], 2.5 KB x2
  __shared__ float lvv[32];

  // stage s2 (whole batch row)
  ((float4*)s2all)[t] = ((const float4*)(s2g + (long)b * 2048))[t];

  const int wave = t >> 6, lane = t & 63;
  const int wm = wave >> 2, wn = wave & 3;
  const int lhi = lane >> 4, llo = lane & 15;
  const int i_p = t >> 4;        // P row (0..31)
  const int jl0 = (t & 15) * 2;  // P j-local base

  // per-P-thread row constants
  const float s1i = s1g[gr0 + i_p];
  const unsigned int ek = s2maxEnc[b];
  const float s2max = (ek & 0x80000000u) ? __uint_as_float(ek & 0x7fffffffu)
                                         : __uint_as_float(~ek);
  const float xm = s1i + s2max;
  const float Mi = fmaxf(xm, ALPHA_LR * xm);

  const int* aptr = adj + (gr0 + i_p) * 2048 + jl0;
  // per-wave B-fragment base: + (f)*32 + j' ushorts, f = wn*64+nt*16+llo, j' = lhi*8
  const unsigned short* wb = WhPack + ((long)b * 64) * 8192 + (wn * 64 + llo) * 32 + lhi * 8;

  // prologue: adj tiles 0 and 1 into regs; B-frags for jt=0 into regs
  int2 aj0 = *(const int2*)aptr;
  int2 aj1 = *(const int2*)(aptr + 32);
  bhalf8 bf[4];
#pragma unroll
  for (int nt = 0; nt < 4; nt++) bf[nt] = *(const bhalf8*)(wb + nt * 512);

  __syncthreads();  // s2all visible

  float lsum;
  {  // P tile 0
    float x0 = s1i + s2all[jl0];
    float x1 = s1i + s2all[jl0 + 1];
    x0 = fmaxf(x0, ALPHA_LR * x0);
    x1 = fmaxf(x1, ALPHA_LR * x1);
    float e0 = (aj0.x > 0) ? __expf(x0 - Mi) : 0.f;
    float e1 = (aj0.y > 0) ? __expf(x1 - Mi) : 0.f;
    lsum = e0 + e1;
    *(unsigned int*)&P[0][i_p * 40 + jl0] =
        (unsigned)f2bf(e0) | ((unsigned)f2bf(e1) << 16);
  }
  __syncthreads();  // P[0] ready

  floatx4 acc[4];
#pragma unroll
  for (int nt = 0; nt < 4; nt++) acc[nt] = (floatx4){0.f, 0.f, 0.f, 0.f};

#pragma unroll 2
  for (int jt = 0; jt < 64; jt++) {
    const int cur = jt & 1, nxt = cur ^ 1;
    bhalf8 bfn[4];
    if (jt < 63) {
      const int jtn = jt + 1;
      // issue next-tile B-frag loads early; they stay in flight across the
      // barrier (reg destination -> no vmcnt drain) and wait at next MFMA use
      const long tb = (long)jtn * 8192;
#pragma unroll
      for (int nt = 0; nt < 4; nt++) bfn[nt] = *(const bhalf8*)(wb + tb + nt * 512);
      const int2 ajc = aj1;
      const int jpf = (jt + 2 < 64) ? jt + 2 : 63;
      aj1 = *(const int2*)(aptr + jpf * 32);  // prefetch
      float x0 = s1i + s2all[jtn * 32 + jl0];
      float x1 = s1i + s2all[jtn * 32 + jl0 + 1];
      x0 = fmaxf(x0, ALPHA_LR * x0);
      x1 = fmaxf(x1, ALPHA_LR * x1);
      float e0 = (ajc.x > 0) ? __expf(x0 - Mi) : 0.f;
      float e1 = (ajc.y > 0) ? __expf(x1 - Mi) : 0.f;
      lsum += e0 + e1;
      *(unsigned int*)&P[nxt][i_p * 40 + jl0] =
          (unsigned)f2bf(e0) | ((unsigned)f2bf(e1) << 16);
    }
    // A-frag from current P buffer + MFMA with current B-frags
    bhalf8 af = *(const bhalf8*)&P[cur][(wm * 16 + llo) * 40 + lhi * 8];
#pragma unroll
    for (int nt = 0; nt < 4; nt++)
      acc[nt] = __builtin_amdgcn_mfma_f32_16x16x32_bf16(af, bf[nt], acc[nt], 0, 0, 0);
    __syncthreads();
#pragma unroll
    for (int nt = 0; nt < 4; nt++) bf[nt] = bfn[nt];
  }

  // denominator: reduce lsum across the 16 lanes sharing row i_p
  lsum += __shfl_xor(lsum, 1);
  lsum += __shfl_xor(lsum, 2);
  lsum += __shfl_xor(lsum, 4);
  lsum += __shfl_xor(lsum, 8);
  if ((t & 15) == 0) lvv[i_p] = 1.f / fmaxf(lsum, 1e-35f);
  __syncthreads();

  // epilogue: normalize, ELU, store. C/D: row = lhi*4+reg, col = llo
#pragma unroll
  for (int nt = 0; nt < 4; nt++) {
#pragma unroll
    for (int reg = 0; reg < 4; reg++) {
      int il = wm * 16 + lhi * 4 + reg;
      int f = wn * 64 + nt * 16 + llo;
      float v = acc[nt][reg] * lvv[il];
      v = v > 0.f ? v : expm1f(v);
      out[(gr0 + il) * 256 + f] = v;
    }
  }
}

// ---------------------------------------------------------------------------
extern "C" void kernel_launch(void* const* d_in, const int* in_sizes, int n_in,
                              void* d_out, int out_size, void* d_ws, size_t ws_size,
                              hipStream_t stream) {
  const float* h = (const float*)d_in[0];
  const int* adj = (const int*)d_in[1];
  const float* W = (const float*)d_in[2];
  const float* a = (const float*)d_in[3];
  float* out = (float*)d_out;

  char* ws = (char*)d_ws;
  unsigned short* WhPack = (unsigned short*)ws;            //  8,388,608 B
  unsigned short* WThi = (unsigned short*)(ws + 8388608);  //    131,072 B
  unsigned short* WTlo = (unsigned short*)(ws + 8519680);  //    131,072 B
  float* s1 = (float*)(ws + 8650752);                      //     65,536 B
  float* s2 = (float*)(ws + 8716288);                      //     65,536 B
  unsigned int* s2maxEnc = (unsigned int*)(ws + 8781824);  //         32 B

  hipLaunchKernelGGL(k0w_split, dim3(16, 16), dim3(16, 16), 0, stream, W, WThi, WTlo, s2maxEnc);
  hipLaunchKernelGGL(k1_mfma, dim3(256), dim3(512), 0, stream, h, WThi, WTlo, a,
                     WhPack, s1, s2, s2maxEnc);
  hipLaunchKernelGGL(k3_attn, dim3(64, 8), dim3(512), 0, stream, WhPack, adj,
                     s1, s2, s2maxEnc, out);
}

// Round 2
// 255.061 us; speedup vs baseline: 1.0818x; 1.0818x over previous
//
#include <hip/hip_runtime.h>

typedef __attribute__((ext_vector_type(8))) short bhalf8;
typedef __attribute__((ext_vector_type(8))) unsigned short ushort8v;
typedef __attribute__((ext_vector_type(4))) float floatx4;

#define ALPHA_LR 0.2f

__device__ __forceinline__ unsigned short f2bf(float f) {
  union { float f; unsigned int u; } v; v.f = f;
  unsigned int r = v.u + 0x7fffu + ((v.u >> 16) & 1u);
  return (unsigned short)(r >> 16);
}
__device__ __forceinline__ float bf2f(unsigned short u) {
  union { unsigned int u; float f; } v; v.u = ((unsigned int)u) << 16;
  return v.f;
}
// async global->LDS, 16B per lane; LDS dest is wave-uniform base + lane*16
__device__ __forceinline__ void gld16(const void* g, void* l) {
  __builtin_amdgcn_global_load_lds((const __attribute__((address_space(1))) unsigned int*)g,
                                   (__attribute__((address_space(3))) unsigned int*)l,
                                   16, 0, 0);
}

// ---------------------------------------------------------------------------
// k0w: W [k][n] fp32 -> WT_hi/WT_lo bf16, k-tiled layout [ks=8][n=256][k'=32].
// Also re-initializes s2maxEnc[8] (ws is re-poisoned before every call).
// ---------------------------------------------------------------------------
__global__ void k0w_split(const float* __restrict__ W,
                          unsigned short* __restrict__ WThi,
                          unsigned short* __restrict__ WTlo,
                          unsigned int* __restrict__ s2maxEnc) {
  __shared__ float s[16][17];
  const int tx = threadIdx.x, ty = threadIdx.y;
  if (blockIdx.x == 0 && blockIdx.y == 0 && ty == 0 && tx < 8) s2maxEnc[tx] = 0u;
  const int n0 = blockIdx.x * 16, k0 = blockIdx.y * 16;
  s[ty][tx] = W[(k0 + ty) * 256 + n0 + tx];
  __syncthreads();
  float v = s[tx][ty];  // = W[k0+tx][n0+ty]
  const int k = k0 + tx, n = n0 + ty;
  unsigned short hi = f2bf(v);
  unsigned short lo = f2bf(v - bf2f(hi));
  const int idx = (k >> 5) * 8192 + n * 32 + (k & 31);
  WThi[idx] = hi;
  WTlo[idx] = lo;
}

// ---------------------------------------------------------------------------
// k1: Wh = h @ W via split-bf16 MFMA (hi*hi + hi*lo + lo*hi), h split in-kernel.
// Writes WhPack bf16 [B][jt=64][f=256][j'=32], s1/s2 (fp32 dots with a), and
// per-batch encoded atomicMax of s2 (for the k3 softmax bound).
// ---------------------------------------------------------------------------
__global__ __launch_bounds__(512, 2) void k1_mfma(const float* __restrict__ h,
                                                  const unsigned short* __restrict__ Bhi_g,
                                                  const unsigned short* __restrict__ Blo_g,
                                                  const float* __restrict__ a_g,
                                                  unsigned short* __restrict__ WhPack,
                                                  float* __restrict__ s1,
                                                  float* __restrict__ s2,
                                                  unsigned int* __restrict__ s2maxEnc) {
  __shared__ unsigned short Ah[64 * 264], Al[64 * 264];  // 33 KB each
  __shared__ unsigned short Bh[2][8192], Bl[2][8192];    // 16 KB per buffer
  __shared__ float s1red[64], s2red[64];
  const int t = threadIdx.x;
  const long r0 = (long)blockIdx.x * 64;
  const int wave = t >> 6, lane = t & 63;

  if (t < 64) { s1red[t] = 0.f; s2red[t] = 0.f; }

#pragma unroll
  for (int rep = 0; rep < 2; rep++) {
    const int off = wave * 1024 + rep * 512;
    gld16(Bhi_g + off + lane * 8, &Bh[0][off]);
    gld16(Blo_g + off + lane * 8, &Bl[0][off]);
  }

#pragma unroll
  for (int q = 0; q < 8; q++) {
    int idx = q * 512 + t;
    int row = idx >> 6, c4 = idx & 63;
    float4 x = *(const float4*)(h + (r0 + row) * 256 + c4 * 4);
    float xs[4] = {x.x, x.y, x.z, x.w};
    unsigned short hs[4], ls[4];
#pragma unroll
    for (int qq = 0; qq < 4; qq++) {
      hs[qq] = f2bf(xs[qq]);
      ls[qq] = f2bf(xs[qq] - bf2f(hs[qq]));
    }
    *(ushort4*)&Ah[row * 264 + c4 * 4] = (ushort4){hs[0], hs[1], hs[2], hs[3]};
    *(ushort4*)&Al[row * 264 + c4 * 4] = (ushort4){ls[0], ls[1], ls[2], ls[3]};
  }
  __syncthreads();

  const int wm = wave >> 2, wn = wave & 3;
  const int lhi = lane >> 4, llo = lane & 15;

  floatx4 acc[2][4];
#pragma unroll
  for (int mt = 0; mt < 2; mt++)
#pragma unroll
    for (int nt = 0; nt < 4; nt++) acc[mt][nt] = (floatx4){0.f, 0.f, 0.f, 0.f};

  for (int ks = 0; ks < 8; ks++) {
    const int cur = ks & 1, nxt = cur ^ 1, ksn = (ks + 1) & 7;
#pragma unroll
    for (int rep = 0; rep < 2; rep++) {
      const int off = wave * 1024 + rep * 512;
      gld16(Bhi_g + ksn * 8192 + off + lane * 8, &Bh[nxt][off]);
      gld16(Blo_g + ksn * 8192 + off + lane * 8, &Bl[nxt][off]);
    }

    const int k0 = ks * 32;
    bhalf8 ah[2], al[2], bh[4], bl[4];
#pragma unroll
    for (int mt = 0; mt < 2; mt++) {
      int ro = (wm * 32 + mt * 16 + llo) * 264 + k0 + lhi * 8;
      ah[mt] = *(const bhalf8*)&Ah[ro];
      al[mt] = *(const bhalf8*)&Al[ro];
    }
#pragma unroll
    for (int nt = 0; nt < 4; nt++) {
      int ro = (wn * 64 + nt * 16 + llo) * 32 + lhi * 8;
      bh[nt] = *(const bhalf8*)&Bh[cur][ro];
      bl[nt] = *(const bhalf8*)&Bl[cur][ro];
    }
#pragma unroll
    for (int mt = 0; mt < 2; mt++)
#pragma unroll
      for (int nt = 0; nt < 4; nt++) {
        acc[mt][nt] = __builtin_amdgcn_mfma_f32_16x16x32_bf16(ah[mt], bh[nt], acc[mt][nt], 0, 0, 0);
        acc[mt][nt] = __builtin_amdgcn_mfma_f32_16x16x32_bf16(ah[mt], bl[nt], acc[mt][nt], 0, 0, 0);
        acc[mt][nt] = __builtin_amdgcn_mfma_f32_16x16x32_bf16(al[mt], bh[nt], acc[mt][nt], 0, 0, 0);
      }
    __syncthreads();
  }

  float a1v[4], a2v[4];
#pragma unroll
  for (int nt = 0; nt < 4; nt++) {
    int f = wn * 64 + nt * 16 + llo;
    a1v[nt] = a_g[f];
    a2v[nt] = a_g[256 + f];
  }

  const int b = (int)(r0 >> 11);
  const int jt_base = (int)((r0 & 2047) >> 5);

#pragma unroll
  for (int mt = 0; mt < 2; mt++) {
    float p1[4], p2[4];
#pragma unroll
    for (int reg = 0; reg < 4; reg++) {
      p1[reg] = acc[mt][0][reg] * a1v[0] + acc[mt][1][reg] * a1v[1] +
                acc[mt][2][reg] * a1v[2] + acc[mt][3][reg] * a1v[3];
      p2[reg] = acc[mt][0][reg] * a2v[0] + acc[mt][1][reg] * a2v[1] +
                acc[mt][2][reg] * a2v[2] + acc[mt][3][reg] * a2v[3];
    }
#pragma unroll
    for (int off = 1; off < 16; off <<= 1) {
#pragma unroll
      for (int reg = 0; reg < 4; reg++) {
        p1[reg] += __shfl_xor(p1[reg], off);
        p2[reg] += __shfl_xor(p2[reg], off);
      }
    }
    if (llo == 0) {
#pragma unroll
      for (int reg = 0; reg < 4; reg++) {
        int il = wm * 32 + mt * 16 + lhi * 4 + reg;
        atomicAdd(&s1red[il], p1[reg]);
        atomicAdd(&s2red[il], p2[reg]);
      }
    }
#pragma unroll
    for (int nt = 0; nt < 4; nt++) {
      int f = wn * 64 + nt * 16 + llo;
      int jt = jt_base + wm;
      ushort4 pk = (ushort4){f2bf(acc[mt][nt][0]), f2bf(acc[mt][nt][1]),
                             f2bf(acc[mt][nt][2]), f2bf(acc[mt][nt][3])};
      *(ushort4*)&WhPack[((long)((b * 64 + jt) * 256 + f)) * 32 + mt * 16 + lhi * 4] = pk;
    }
  }

  __syncthreads();
  if (t < 64) {
    s1[r0 + t] = s1red[t];
    s2[r0 + t] = s2red[t];
    // per-batch max(s2): 64-lane reduce + one encoded atomicMax per block
    float v = s2red[t];
#pragma unroll
    for (int o = 32; o; o >>= 1) v = fmaxf(v, __shfl_xor(v, o));
    if (t == 0) {
      unsigned int u = __float_as_uint(v);
      unsigned int key = (u & 0x80000000u) ? ~u : (u | 0x80000000u);
      atomicMax(s2maxEnc + b, key);
    }
  }
}

// ---------------------------------------------------------------------------
// K3 v3 (chunked raw-barrier pipeline): out = elu(softmax(mask(leaky(s1+s2)))@Wh)
// - Wh read L2-direct into regs (1 MB/batch fits per-XCD L2; XCD-affine b=lin&7).
// - j-loop chunked: 4 MFMA-tiles (128 j) per phase, ONE raw s_barrier per phase
//   (s_waitcnt lgkmcnt(0) only -> global reg loads stay in flight across it;
//   __syncthreads would drain vmcnt(0) and expose L2 latency per tile, which is
//   what regressed round 1).
// - B frags single-buffered in regs: tile tl's next-chunk load issued right
//   after its MFMA (WAR reuse, ~1 chunk in flight > L2 latency).
// - adj prefetched 2 chunks ahead (ping-pong int4 pairs).
// - Waves: each wave owns all 32 rows x 32 cols (mt 0..1 x nt 0..1).
// LDS ~25.7 KB; grid (64,8) x 512 thr.
// ---------------------------------------------------------------------------
__global__ __launch_bounds__(512, 4) void k3_attn(const unsigned short* __restrict__ WhPack,
                                                  const int* __restrict__ adj,
                                                  const float* __restrict__ s1g,
                                                  const float* __restrict__ s2g,
                                                  const unsigned int* __restrict__ s2maxEnc,
                                                  float* __restrict__ out) {
  const int t = threadIdx.x;
  const int lin = blockIdx.y * 64 + blockIdx.x;
  const int b = lin & 7;  // XCD-affine: round-robin dispatch -> XCD = lin%8
  const int i0 = (lin >> 3) * 32;
  const long gr0 = (long)b * 2048 + i0;

  __shared__ float s2all[2048];              // 8 KB
  __shared__ unsigned short P[2][32 * 136];  // 2 x 8.5 KB (pad 136 -> ~2-way banks)
  __shared__ float lvv[32];

  // stage s2 (whole batch row)
  ((float4*)s2all)[t] = ((const float4*)(s2g + (long)b * 2048))[t];

  const int wave = t >> 6, lane = t & 63;
  const int lhi = lane >> 4, llo = lane & 15;
  const int i_p = t >> 4;        // P row (0..31)
  const int jl = (t & 15) * 8;   // P chunk-local j base (8 per thread)

  const float s1i = s1g[gr0 + i_p];
  const unsigned int ek = s2maxEnc[b];
  const float s2max = (ek & 0x80000000u) ? __uint_as_float(ek & 0x7fffffffu)
                                         : __uint_as_float(~ek);
  const float xm = s1i + s2max;
  const float Mi = fmaxf(xm, ALPHA_LR * xm);

  const int* aptr = adj + (gr0 + i_p) * 2048 + jl;  // + chunk*128
  // B-frag base: f = wave*32 + nt*16 + llo, j' = lhi*8; frag at + jt*8192 + nt*512
  const unsigned short* wb =
      WhPack + ((long)b) * 524288 + (long)(wave * 1024 + llo * 32 + lhi * 8);

  // adj prefetch: ADJ[c] = this thread's 8 ints of chunk c
  int4 ajP0 = *(const int4*)(aptr);        // ADJ[0] (prologue use)
  int4 ajP1 = *(const int4*)(aptr + 4);
  int4 ajO0 = *(const int4*)(aptr + 128);  // ADJ[1] -> consumed by even chunks
  int4 ajO1 = *(const int4*)(aptr + 132);
  int4 ajE0 = *(const int4*)(aptr + 256);  // ADJ[2] -> consumed by odd chunks
  int4 ajE1 = *(const int4*)(aptr + 260);

  // B chunk 0 (tiles 0..3) into regs
  bhalf8 bF[4][2];
#pragma unroll
  for (int tl = 0; tl < 4; tl++) {
    bF[tl][0] = *(const bhalf8*)(wb + (long)tl * 8192);
    bF[tl][1] = *(const bhalf8*)(wb + (long)tl * 8192 + 512);
  }

  __syncthreads();  // s2all visible (one-time vmcnt drain, harmless)

  float lsum = 0.f;
  // P chunk 0 -> P[0]
  {
    float4 sA = *(const float4*)&s2all[jl];
    float4 sB = *(const float4*)&s2all[jl + 4];
    float xs[8] = {sA.x, sA.y, sA.z, sA.w, sB.x, sB.y, sB.z, sB.w};
    int am[8] = {ajP0.x, ajP0.y, ajP0.z, ajP0.w, ajP1.x, ajP1.y, ajP1.z, ajP1.w};
    unsigned short pe[8];
#pragma unroll
    for (int q = 0; q < 8; q++) {
      float x = s1i + xs[q];
      x = fmaxf(x, ALPHA_LR * x);
      float e = (am[q] > 0) ? __expf(x - Mi) : 0.f;
      lsum += e;
      pe[q] = f2bf(e);
    }
    *(ushort8v*)&P[0][i_p * 136 + jl] =
        (ushort8v){pe[0], pe[1], pe[2], pe[3], pe[4], pe[5], pe[6], pe[7]};
  }
  asm volatile("s_waitcnt lgkmcnt(0)\n\ts_barrier" ::: "memory");

  floatx4 acc[2][2];
#pragma unroll
  for (int mt = 0; mt < 2; mt++)
#pragma unroll
    for (int nt = 0; nt < 2; nt++) acc[mt][nt] = (floatx4){0.f, 0.f, 0.f, 0.f};

  // Per chunk cc: compute P for chunk cc+1 into P[nxt]; reload adj 2 ahead;
  // 16 MFMA on P[cur] x bF; per tile, reissue bF with chunk cc+1's data
  // (stays in flight across the raw barrier); lgkmcnt(0)+s_barrier.
#define CHUNK_BODY(cc, AJ0, AJ1)                                                   \
  {                                                                                \
    const int cur = (cc) & 1, nxt = cur ^ 1;                                       \
    if ((cc) < 15) {                                                               \
      float4 sA = *(const float4*)&s2all[((cc) + 1) * 128 + jl];                   \
      float4 sB = *(const float4*)&s2all[((cc) + 1) * 128 + jl + 4];               \
      float xs[8] = {sA.x, sA.y, sA.z, sA.w, sB.x, sB.y, sB.z, sB.w};              \
      int am[8] = {AJ0.x, AJ0.y, AJ0.z, AJ0.w, AJ1.x, AJ1.y, AJ1.z, AJ1.w};        \
      unsigned short pe[8];                                                        \
      _Pragma("unroll") for (int q = 0; q < 8; q++) {                              \
        float x = s1i + xs[q];                                                     \
        x = fmaxf(x, ALPHA_LR * x);                                                \
        float e = (am[q] > 0) ? __expf(x - Mi) : 0.f;                              \
        lsum += e;                                                                 \
        pe[q] = f2bf(e);                                                           \
      }                                                                            \
      *(ushort8v*)&P[nxt][i_p * 136 + jl] =                                        \
          (ushort8v){pe[0], pe[1], pe[2], pe[3], pe[4], pe[5], pe[6], pe[7]};      \
    }                                                                              \
    if ((cc) < 13) {                                                               \
      AJ0 = *(const int4*)(aptr + ((cc) + 3) * 128);                               \
      AJ1 = *(const int4*)(aptr + ((cc) + 3) * 128 + 4);                           \
    }                                                                              \
    const long jt4 = (long)((((cc) < 15) ? (cc) + 1 : 15) * 4) * 8192;             \
    _Pragma("unroll") for (int tl = 0; tl < 4; tl++) {                             \
      bhalf8 af0 = *(const bhalf8*)&P[cur][llo * 136 + tl * 32 + lhi * 8];         \
      bhalf8 af1 = *(const bhalf8*)&P[cur][(16 + llo) * 136 + tl * 32 + lhi * 8];  \
      acc[0][0] = __builtin_amdgcn_mfma_f32_16x16x32_bf16(af0, bF[tl][0], acc[0][0], 0, 0, 0); \
      acc[0][1] = __builtin_amdgcn_mfma_f32_16x16x32_bf16(af0, bF[tl][1], acc[0][1], 0, 0, 0); \
      acc[1][0] = __builtin_amdgcn_mfma_f32_16x16x32_bf16(af1, bF[tl][0], acc[1][0], 0, 0, 0); \
      acc[1][1] = __builtin_amdgcn_mfma_f32_16x16x32_bf16(af1, bF[tl][1], acc[1][1], 0, 0, 0); \
      bF[tl][0] = *(const bhalf8*)(wb + jt4 + (long)tl * 8192);                    \
      bF[tl][1] = *(const bhalf8*)(wb + jt4 + (long)tl * 8192 + 512);              \
    }                                                                              \
    asm volatile("s_waitcnt lgkmcnt(0)\n\ts_barrier" ::: "memory");                \
  }

  for (int c2 = 0; c2 < 8; c2++) {
    CHUNK_BODY(c2 * 2, ajO0, ajO1);
    CHUNK_BODY(c2 * 2 + 1, ajE0, ajE1);
  }
#undef CHUNK_BODY

  // denominator: reduce lsum across the 16 lanes sharing row i_p
  lsum += __shfl_xor(lsum, 1);
  lsum += __shfl_xor(lsum, 2);
  lsum += __shfl_xor(lsum, 4);
  lsum += __shfl_xor(lsum, 8);
  if ((t & 15) == 0) lvv[i_p] = 1.f / fmaxf(lsum, 1e-35f);
  __syncthreads();

  // epilogue: normalize, ELU, store. C/D: row = lhi*4+reg, col = llo
#pragma unroll
  for (int mt = 0; mt < 2; mt++) {
#pragma unroll
    for (int nt = 0; nt < 2; nt++) {
#pragma unroll
      for (int reg = 0; reg < 4; reg++) {
        int il = mt * 16 + lhi * 4 + reg;
        int f = wave * 32 + nt * 16 + llo;
        float v = acc[mt][nt][reg] * lvv[il];
        v = v > 0.f ? v : expm1f(v);
        out[(gr0 + il) * 256 + f] = v;
      }
    }
  }
}

// ---------------------------------------------------------------------------
extern "C" void kernel_launch(void* const* d_in, const int* in_sizes, int n_in,
                              void* d_out, int out_size, void* d_ws, size_t ws_size,
                              hipStream_t stream) {
  const float* h = (const float*)d_in[0];
  const int* adj = (const int*)d_in[1];
  const float* W = (const float*)d_in[2];
  const float* a = (const float*)d_in[3];
  float* out = (float*)d_out;

  char* ws = (char*)d_ws;
  unsigned short* WhPack = (unsigned short*)ws;            //  8,388,608 B
  unsigned short* WThi = (unsigned short*)(ws + 8388608);  //    131,072 B
  unsigned short* WTlo = (unsigned short*)(ws + 8519680);  //    131,072 B
  float* s1 = (float*)(ws + 8650752);                      //     65,536 B
  float* s2 = (float*)(ws + 8716288);                      //     65,536 B
  unsigned int* s2maxEnc = (unsigned int*)(ws + 8781824);  //         32 B

  hipLaunchKernelGGL(k0w_split, dim3(16, 16), dim3(16, 16), 0, stream, W, WThi, WTlo, s2maxEnc);
  hipLaunchKernelGGL(k1_mfma, dim3(256), dim3(512), 0, stream, h, WThi, WTlo, a,
                     WhPack, s1, s2, s2maxEnc);
  hipLaunchKernelGGL(k3_attn, dim3(64, 8), dim3(512), 0, stream, WhPack, adj,
                     s1, s2, s2maxEnc, out);
}